// Round 3
// baseline (239.851 us; speedup 1.0000x reference)
//
#include <hip/hip_runtime.h>

typedef __bf16 bf16_t;
typedef __bf16 bf16x4_t __attribute__((ext_vector_type(4)));
typedef __bf16 bf16x8_t __attribute__((ext_vector_type(8)));
typedef float f32x16_t __attribute__((ext_vector_type(16)));

// ---------------------------------------------------------------------------
// Repack weight (oc, ic, ky, kx) fp32 -> bf16 [t=ky*3+kx][oc][ic]
// ---------------------------------------------------------------------------
__global__ __launch_bounds__(256) void repack_kernel(const float* __restrict__ w,
                                                     bf16_t* __restrict__ wt) {
  int flat = blockIdx.x * 256 + threadIdx.x;  // 9*128*128 = 147456 exact
  int t = flat >> 14;                         // tap 0..8
  int rem = flat & 16383;                     // oc*128 + ic
  wt[flat] = (bf16_t)w[(size_t)rem * 9 + t];
}

// ---------------------------------------------------------------------------
// DWT: in fp32 (B,32,2h,2w) -> sub bf16 NHWC (B,h,w,128) ci=4c+q, ll fp32 (B,32,h,w)
// block: 256 thr = 64 j-lanes x 4 c-groups; one (b, i, 64-j chunk) per block
// ---------------------------------------------------------------------------
__global__ __launch_bounds__(256) void dwt_kernel(const float* __restrict__ in,
                                                  bf16_t* __restrict__ sub,
                                                  float* __restrict__ llout,
                                                  int h, int w) {
  __shared__ __align__(16) bf16_t lds[64 * 132];  // stride 132 (264B, 8B-aligned, ~2-way)
  const int bi = blockIdx.z;
  const int i = blockIdx.y;
  const int j0 = blockIdx.x * 64;
  const int tid = threadIdx.x;
  const int j = tid & 63;
  const int cg = tid >> 6;
  const int jg = j0 + j;
  const bool jok = jg < w;
  const int H2 = h * 2, W2 = w * 2;
  for (int c = cg; c < 32; c += 4) {
    float va = 0.f, vb = 0.f, vc = 0.f, vd = 0.f;
    if (jok) {
      const float2* p0 = (const float2*)(in + ((size_t)(bi * 32 + c) * H2 + 2 * i) * W2);
      const float2* p1 = (const float2*)(in + ((size_t)(bi * 32 + c) * H2 + 2 * i + 1) * W2);
      float2 r0 = p0[jg];
      float2 r1 = p1[jg];
      va = r0.x; vb = r0.y; vc = r1.x; vd = r1.y;
    }
    float ll = (va + vb + vc + vd) * 0.5f;
    float lh = (va - vb + vc - vd) * 0.5f;
    float hl = (va + vb - vc - vd) * 0.5f;
    float hh = (va - vb - vc + vd) * 0.5f;
    bf16x4_t q;
    q.x = (bf16_t)ll; q.y = (bf16_t)lh; q.z = (bf16_t)hl; q.w = (bf16_t)hh;
    *(bf16x4_t*)(&lds[j * 132 + c * 4]) = q;
    if (llout != nullptr && jok)
      llout[((size_t)(bi * 32 + c) * h + i) * w + jg] = ll;
  }
  __syncthreads();
  const size_t obase = ((size_t)bi * h + i) * w;
  for (int it = 0; it < 8; ++it) {
    int flat = it * 256 + tid;  // 2048 slots of 4 bf16
    int jj = flat >> 5;
    int c4 = flat & 31;
    if (j0 + jj < w) {
      bf16x4_t q = *(const bf16x4_t*)(&lds[jj * 132 + c4 * 4]);
      *(bf16x4_t*)(sub + ((obase + j0 + jj) << 7) + c4 * 4) = q;
    }
  }
}

// ---------------------------------------------------------------------------
// Conv 3x3 pad1, 128->128ch, implicit GEMM with MFMA 32x32x16 bf16.
// Block: 8x16 spatial tile (M=128) x N=128, 4 waves (2x2), wave tile 64x64.
// LDS: halo 10x18 pix x 16 chunks(16B) swizzled (46080 B) + B-half 128oc x 64ic
// swizzled (16384 B) = 62464 B -> 2 blocks/CU.
// ---------------------------------------------------------------------------
__global__ __launch_bounds__(256, 2) void conv_kernel(const bf16_t* __restrict__ sub,
                                                      const bf16_t* __restrict__ wt,
                                                      float* __restrict__ y,
                                                      int h, int w) {
  __shared__ uint4 smemv[3904];            // 62464 B, 16B aligned
  char* haloS = (char*)smemv;              // 46080 B
  char* Bs = (char*)smemv + 46080;         // 16384 B
  const int bi = blockIdx.z;
  const int y0 = blockIdx.y * 8;
  const int x0 = blockIdx.x * 16;
  const int tid = threadIdx.x;
  const size_t img_base = (size_t)bi * h * w;

  // ---- stage halo: 180 pixels x 16 chunks of 16B, zero-filled borders ----
  for (int it = 0; it < 12; ++it) {
    int flat = it * 256 + tid;
    int pix = flat >> 4;
    int ch = flat & 15;
    if (pix < 180) {
      int r = pix / 18;
      int c = pix - r * 18;
      int gy = y0 + r - 1;
      int gx = x0 + c - 1;
      uint4 v = make_uint4(0u, 0u, 0u, 0u);
      if ((unsigned)gy < (unsigned)h && (unsigned)gx < (unsigned)w)
        v = *(const uint4*)(sub + ((img_base + (size_t)gy * w + gx) << 7) + (ch << 3));
      *(uint4*)(haloS + (pix << 8) + ((ch ^ (pix & 7)) << 4)) = v;
    }
  }

  const int lane = tid & 63;
  const int wav = tid >> 6;
  const int wr = wav >> 1;                 // wave row (0/1): spatial rows wr*4..+3
  const int wc = wav & 1;                  // wave col: oc base wc*64
  const int m = lane & 31;                 // A-operand m index (pixel in 32-tile)
  const int hw_ = lane >> 5;               // half-wave: k offset hw_*8
  const int il = wr * 4 + (m >> 4);        // local out row (mt=0)
  const int jl = m & 15;                   // local out col
  const int pixA = il * 18 + jl;
  const int oc0 = wc * 64 + m;             // nt=0 col; nt=1 -> +32
  const int sB = oc0 & 7;                  // (oc0+32)&7 == oc0&7

  f32x16_t acc[2][2] = {};

  for (int t = 0; t < 9; ++t) {
    const int ky = t / 3;
    const int kx = t - ky * 3;
    const int pix0 = pixA + ky * 18 + kx;
    const int pix1 = pix0 + 36;            // mt=1: +2 spatial rows
    const int s0 = pix0 & 7;
    const int s1 = pix1 & 7;
    for (int hk = 0; hk < 2; ++hk) {       // 64-ic halves of the tap
      __syncthreads();                     // prior readers of Bs done
      const bf16_t* wsrc = wt + (t << 14) + (hk << 6);
      for (int it = 0; it < 4; ++it) {
        int flat = it * 256 + tid;         // 1024 slots of 16B (8 ic)
        int oc = flat >> 3;
        int ch = flat & 7;
        uint4 v = *(const uint4*)(wsrc + (oc << 7) + (ch << 3));
        *(uint4*)(Bs + (oc << 7) + ((ch ^ (oc & 7)) << 4)) = v;
      }
      __syncthreads();
      const char* hp0 = haloS + (pix0 << 8) + (hk << 7);
      const char* hp1 = haloS + (pix1 << 8) + (hk << 7);
      const char* bp0 = Bs + (oc0 << 7);
      const char* bp1 = Bs + ((oc0 + 32) << 7);
#pragma unroll
      for (int kc = 0; kc < 4; ++kc) {
        const int cidx = kc * 2 + hw_;     // 16B chunk within the 64-ic half
        bf16x8_t a0 = *(const bf16x8_t*)(hp0 + ((cidx ^ s0) << 4));
        bf16x8_t a1 = *(const bf16x8_t*)(hp1 + ((cidx ^ s1) << 4));
        bf16x8_t b0 = *(const bf16x8_t*)(bp0 + ((cidx ^ sB) << 4));
        bf16x8_t b1 = *(const bf16x8_t*)(bp1 + ((cidx ^ sB) << 4));
        acc[0][0] = __builtin_amdgcn_mfma_f32_32x32x16_bf16(a0, b0, acc[0][0], 0, 0, 0);
        acc[0][1] = __builtin_amdgcn_mfma_f32_32x32x16_bf16(a0, b1, acc[0][1], 0, 0, 0);
        acc[1][0] = __builtin_amdgcn_mfma_f32_32x32x16_bf16(a1, b0, acc[1][0], 0, 0, 0);
        acc[1][1] = __builtin_amdgcn_mfma_f32_32x32x16_bf16(a1, b1, acc[1][1], 0, 0, 0);
      }
    }
  }

  // epilogue: D row=(reg&3)+8*(reg>>2)+4*hw_, col=lane&31 (m74/m101 verified)
#pragma unroll
  for (int mt = 0; mt < 2; ++mt) {
#pragma unroll
    for (int reg = 0; reg < 16; ++reg) {
      int row = (reg & 3) + ((reg >> 2) << 3) + (hw_ << 2);
      int p = wr * 64 + mt * 32 + row;
      int gy = y0 + (p >> 4);
      int gx = x0 + (p & 15);
      if (gy < h && gx < w) {
        float* yp = y + ((img_base + (size_t)gy * w + gx) << 7);
        yp[oc0] = acc[mt][0][reg];
        yp[oc0 + 32] = acc[mt][1][reg];
      }
    }
  }
}

// ---------------------------------------------------------------------------
// IDWT: y fp32 NHWC (B,h,w,128) [+ nll fp32 (B,32,h,w)] [+ bias] -> out fp32 (B,32,2h,2w)
// ---------------------------------------------------------------------------
__global__ __launch_bounds__(256) void idwt_kernel(const float* __restrict__ y,
                                                   const float* __restrict__ nll,
                                                   const float* __restrict__ bias,
                                                   float* __restrict__ out,
                                                   int h, int w) {
  __shared__ __align__(16) float lds[32 * 132];
  const int bi = blockIdx.z;
  const int i = blockIdx.y;
  const int j0 = blockIdx.x * 32;
  const int tid = threadIdx.x;
  const size_t ybase = ((size_t)bi * h + i) * w;
  for (int it = 0; it < 4; ++it) {
    int flat = it * 256 + tid;  // 1024 float4 slots
    int jj = flat >> 5;
    int c4 = flat & 31;
    if (j0 + jj < w) {
      float4 v = *(const float4*)(y + ((ybase + j0 + jj) << 7) + c4 * 4);
      *(float4*)(&lds[jj * 132 + c4 * 4]) = v;
    }
  }
  __syncthreads();
  const int j = tid & 31;
  const int c0 = tid >> 5;
  const int jg = j0 + j;
  if (jg >= w) return;
  const int W2 = w * 2;
  for (int c = c0; c < 32; c += 8) {
    float4 s = *(const float4*)(&lds[j * 132 + c * 4]);
    float ll = s.x, lh = s.y, hl = s.z, hh = s.w;
    if (nll != nullptr) ll += nll[((size_t)(bi * 32 + c) * h + i) * w + jg];
    float a = (ll + lh + hl + hh) * 0.5f;
    float b2 = (ll - lh + hl - hh) * 0.5f;
    float c2 = (ll + lh - hl - hh) * 0.5f;
    float d2 = (ll - lh - hl + hh) * 0.5f;
    if (bias != nullptr) {
      float bv = bias[c];
      a += bv; b2 += bv; c2 += bv; d2 += bv;
    }
    float* o0 = out + ((size_t)(bi * 32 + c) * (2 * h) + 2 * i) * W2 + 2 * jg;
    *(float2*)o0 = make_float2(a, b2);
    *(float2*)(o0 + W2) = make_float2(c2, d2);
  }
}

// ---------------------------------------------------------------------------
// Workspace layout (bytes, peak 96,632,832):
//   wt    @ 0         (294,912)
//   A     @ 294,912   sub0 (25,690,112); after conv0 reused for:
//                     sub1 @ 294,912 (6,422,528), sub2 @ 6,717,440 (1,605,632),
//                     nll2 @ 8,323,072 (802,816), nll1 @ 11,534,336 (3,211,264)
//   B     @ 25,985,024 ll0 (12,845,056); after dwt1 reused for y1 (12,845,056)
//   C     @ 38,830,080 y0 (51,380,224)
//   D     @ 90,210,304 ll1 (3,211,264); y2 @ 93,421,568 (3,211,264)
// ---------------------------------------------------------------------------
extern "C" void kernel_launch(void* const* d_in, const int* in_sizes, int n_in,
                              void* d_out, int out_size, void* d_ws, size_t ws_size,
                              hipStream_t stream) {
  // Defensive: if the harness workspace is smaller than our peak footprint,
  // do NOT launch (OOB ws writes could hard-fault the GPU / kill the container).
  // A clean absmax failure then tells us ws_size is the constraint.
  if (ws_size < 96632832u) return;

  const float* x = (const float*)d_in[0];
  const float* weight = (const float*)d_in[1];
  const float* bias = (const float*)d_in[2];
  float* out = (float*)d_out;
  char* ws = (char*)d_ws;

  bf16_t* wt = (bf16_t*)(ws);
  bf16_t* sub0 = (bf16_t*)(ws + 294912);
  bf16_t* sub1 = (bf16_t*)(ws + 294912);
  bf16_t* sub2 = (bf16_t*)(ws + 6717440);
  float* nll2 = (float*)(ws + 8323072);
  float* nll1 = (float*)(ws + 11534336);
  float* ll0 = (float*)(ws + 25985024);
  float* y1 = (float*)(ws + 25985024);
  float* y0 = (float*)(ws + 38830080);
  float* ll1 = (float*)(ws + 90210304);
  float* y2 = (float*)(ws + 93421568);

  repack_kernel<<<576, 256, 0, stream>>>(weight, wt);

  // level 0: 224 -> 112
  dwt_kernel<<<dim3(2, 112, 8), 256, 0, stream>>>(x, sub0, ll0, 112, 112);
  conv_kernel<<<dim3(7, 14, 8), 256, 0, stream>>>(sub0, wt, y0, 112, 112);
  // level 1: 112 -> 56
  dwt_kernel<<<dim3(1, 56, 8), 256, 0, stream>>>(ll0, sub1, ll1, 56, 56);
  conv_kernel<<<dim3(4, 7, 8), 256, 0, stream>>>(sub1, wt, y1, 56, 56);
  // level 2: 56 -> 28
  dwt_kernel<<<dim3(1, 28, 8), 256, 0, stream>>>(ll1, sub2, nullptr, 28, 28);
  conv_kernel<<<dim3(2, 4, 8), 256, 0, stream>>>(sub2, wt, y2, 28, 28);
  // inverse chain
  idwt_kernel<<<dim3(1, 28, 8), 256, 0, stream>>>(y2, nullptr, nullptr, nll2, 28, 28);
  idwt_kernel<<<dim3(2, 56, 8), 256, 0, stream>>>(y1, nll2, nullptr, nll1, 56, 56);
  idwt_kernel<<<dim3(4, 112, 8), 256, 0, stream>>>(y0, nll1, bias, out, 112, 112);
}